// Round 18
// baseline (191.096 us; speedup 1.0000x reference)
//
#include <hip/hip_runtime.h>
#include <math.h>

#define HEADS     8
#define LEVELS    4
#define POINTS    4
#define HEAD_DIM  32
#define EMBED     256
#define NQ        19947
#define NV        19947
#define BS        2
#define M_ROWS    (BS * NQ)   // 39894
#define MT        624         // M tiles of 64 rows

typedef _Float16 h8 __attribute__((ext_vector_type(8)));
typedef _Float16 h4 __attribute__((ext_vector_type(4)));
typedef _Float16 h2 __attribute__((ext_vector_type(2)));
typedef float    f32x4 __attribute__((ext_vector_type(4)));
typedef unsigned short ushort8 __attribute__((ext_vector_type(8)));

static __device__ __forceinline__ int lvl_H(int l) {
    constexpr int v[4] = {100, 50, 25, 13}; return v[l];
}
static __device__ __forceinline__ int lvl_W(int l) {
    constexpr int v[4] = {150, 75, 38, 19}; return v[l];
}
static __device__ __forceinline__ int lvl_start(int l) {
    constexpr int v[4] = {0, 15000, 18750, 19700}; return v[l];
}

// f32 -> f16 bits (RTNE via hardware cvt)
static __device__ __forceinline__ unsigned short f2h(float f) {
    _Float16 h = (_Float16)f;
    return __builtin_bit_cast(unsigned short, h);
}

// async global->LDS, 16B per lane (kept for reference; GEMMs now reg-stage)
static __device__ __forceinline__ void gload_lds16(const void* g, void* l) {
    __builtin_amdgcn_global_load_lds(
        (const __attribute__((address_space(1))) void*)g,
        (__attribute__((address_space(3))) void*)l, 16, 0, 0);
}

// packed f16 FMA, weight pre-splatted as u32 {w,w}
static __device__ __forceinline__ void pkacc_u(h2* acc, uint4 u, unsigned wbits) {
    const h2 wv = __builtin_bit_cast(h2, wbits);
    acc[0] = __builtin_bit_cast(h2, u.x) * wv + acc[0];
    acc[1] = __builtin_bit_cast(h2, u.y) * wv + acc[1];
    acc[2] = __builtin_bit_cast(h2, u.z) * wv + acc[2];
    acc[3] = __builtin_bit_cast(h2, u.w) * wv + acc[3];
}

// ---------------------------------------------------------------------------
// Pack weights only: Wcat[640][256] = [W_val^T; W_off^T; W_attn^T], WoutT.
// ---------------------------------------------------------------------------
__global__ __launch_bounds__(256) void pack_weights_kernel(
    const float* __restrict__ Wv, const float* __restrict__ Wo,
    const float* __restrict__ Wa, const float* __restrict__ Wout,
    unsigned short* __restrict__ Wcat, unsigned short* __restrict__ WoutT)
{
    const int tid = blockIdx.x * 256 + threadIdx.x;
    if (tid >= 896 * 32) return;
    const int row = tid >> 5;
    const int k8  = tid & 31;
    const float* src; int n_local, N; unsigned short* dstb; int r_local;
    if (row < 256)      { src = Wv;   n_local = row;       N = 256; dstb = Wcat;  r_local = row; }
    else if (row < 512) { src = Wo;   n_local = row - 256; N = 256; dstb = Wcat;  r_local = row; }
    else if (row < 640) { src = Wa;   n_local = row - 512; N = 128; dstb = Wcat;  r_local = row; }
    else                { src = Wout; n_local = row - 640; N = 256; dstb = WoutT; r_local = row - 640; }
    const int k = k8 * 8;
    ushort8 o;
    #pragma unroll
    for (int j = 0; j < 8; ++j)
        o[j] = f2h(src[(size_t)(k + j) * N + n_local]);
    const int g  = k8 >> 3;
    const int u2 = (k8 & 7) ^ (r_local & 7);
    *(ushort8*)((char*)dstb + (size_t)r_local * 512 + g * 128 + u2 * 16) = o;
}

// ---------------------------------------------------------------------------
// f16 MFMA GEMM, 64x128 tile, BK=64, 4 waves, LDS 24KB single-buffer.
// T14 async-STAGE split: global loads for step ks+1 issued into REGISTERS
// before compute(ks); ds_write after the post-compute barrier. The vmcnt
// drain thus lands ~a full compute-phase after issue (latency hidden).
// 1D grid, XCD-affinity remap.
// EPI 0 (NB=5): A from query f32 (cvt f16 + swizzled ds_write).
// EPI 1 (NB=2): A from oabf (pre-swizzled f16, linear ds_write);
//               out = acc + b_out + query (f32 residual)
// ---------------------------------------------------------------------------
template <int EPI>
__global__ __launch_bounds__(256) void mfma_gemm_kernel(
    const float* __restrict__ Aq,            // EPI0: query f32 [M][256]
    const unsigned short* __restrict__ Ah,   // EPI1: oabf (swizzled f16)
    const unsigned short* __restrict__ Bh,
    unsigned short* __restrict__ value_h,    // EPI0
    unsigned short* __restrict__ oa,         // EPI0: [M][384] f16
    const float* __restrict__ b_val, const float* __restrict__ b_off,
    const float* __restrict__ b_attn,
    const float* __restrict__ b_out,
    const float* __restrict__ qres,          // EPI1: query f32 residual
    float* __restrict__ out)
{
    __shared__ alignas(16) char As[8192];    // 64 rows x 64 k f16
    __shared__ alignas(16) char Bs[16384];   // 128 rows x 64 k f16

    constexpr int NB = (EPI == 0) ? 5 : 2;
    const int id  = blockIdx.x;
    const int grp = id / (8 * NB);
    const int rem = id - grp * (8 * NB);
    const int bx  = grp * 8 + (rem & 7);
    const int by  = rem >> 3;

    const int t    = threadIdx.x;
    const int wid  = t >> 6;
    const int lane = t & 63;
    const int l15  = lane & 15;
    const int lhi  = lane >> 4;
    const int m0   = bx * 64;
    const int n0   = by * 128;

    f32x4 acc[4][2] = {};

    uint4 aR[2];    // staged A units (16B each)
    uint4 bR[4];    // staged B units

    auto ld = [&](int ks) {
        #pragma unroll
        for (int j = 0; j < 2; ++j) {
            const int q  = j * 256 + t;
            const int tr = q >> 3;
            const int u  = q & 7;
            int gr = m0 + tr; gr = gr < M_ROWS ? gr : (M_ROWS - 1);
            if (EPI == 0) {
                const float* src = Aq + (size_t)gr * 256 + ks * 64 + u * 8;
                const float4 v0 = *(const float4*)(src);
                const float4 v1 = *(const float4*)(src + 4);
                ushort8 o;
                o[0] = f2h(v0.x); o[1] = f2h(v0.y);
                o[2] = f2h(v0.z); o[3] = f2h(v0.w);
                o[4] = f2h(v1.x); o[5] = f2h(v1.y);
                o[6] = f2h(v1.z); o[7] = f2h(v1.w);
                aR[j] = *(uint4*)&o;
            } else {
                aR[j] = *(const uint4*)((const char*)Ah +
                        (size_t)gr * 512 + ks * 128 + u * 16);
            }
        }
        #pragma unroll
        for (int j = 0; j < 4; ++j) {
            const int q  = j * 256 + t;
            const int tr = q >> 3;
            const int u  = q & 7;
            const int gn = n0 + tr;
            bR[j] = *(const uint4*)((const char*)Bh +
                    (size_t)gn * 512 + ks * 128 + u * 16);
        }
    };

    auto wr = [&]() {
        #pragma unroll
        for (int j = 0; j < 2; ++j) {
            const int q  = j * 256 + t;
            const int tr = q >> 3;
            const int u  = q & 7;
            if (EPI == 0)
                *(uint4*)&As[tr * 128 + (unsigned)(u ^ (tr & 7)) * 16] = aR[j];
            else
                *(uint4*)&As[q * 16] = aR[j];   // source pre-swizzled
        }
        #pragma unroll
        for (int j = 0; j < 4; ++j)
            *(uint4*)&Bs[(j * 256 + t) * 16] = bR[j];
    };

    ld(0);
    wr();
    __syncthreads();
    for (int ks = 0; ks < 4; ++ks) {
        if (ks < 3) ld(ks + 1);          // issue next-step loads (latency hides under compute)
        #pragma unroll
        for (int kc = 0; kc < 2; ++kc) {
            h8 a[4], b[2];
            #pragma unroll
            for (int i = 0; i < 4; ++i) {
                const int tr = i * 16 + l15;
                const int ua = (kc * 4 + lhi) ^ (tr & 7);
                a[i] = *(const h8*)&As[tr * 128 + ua * 16];
            }
            #pragma unroll
            for (int j2 = 0; j2 < 2; ++j2) {
                const int tn = wid * 32 + j2 * 16 + l15;
                const int ub = (kc * 4 + lhi) ^ (tn & 7);
                b[j2] = *(const h8*)&Bs[tn * 128 + ub * 16];
            }
            #pragma unroll
            for (int i = 0; i < 4; ++i)
                #pragma unroll
                for (int j2 = 0; j2 < 2; ++j2)
                    acc[i][j2] = __builtin_amdgcn_mfma_f32_16x16x32_f16(
                        a[i], b[j2], acc[i][j2], 0, 0, 0);
        }
        if (ks < 3) {
            __syncthreads();             // all reads of LDS done (drains loads too)
            wr();                        // publish next tile
            __syncthreads();
        }
    }

    if (EPI == 0) {
        if (by < 2) {
            // value projection -> f16 [2][8][NV][32]
            #pragma unroll
            for (int j2 = 0; j2 < 2; ++j2) {
                const int gn = n0 + wid * 32 + j2 * 16 + l15;
                const float bias = b_val[gn];
                const int h = gn >> 5, ch = gn & 31;
                #pragma unroll
                for (int i = 0; i < 4; ++i) {
                    #pragma unroll
                    for (int r = 0; r < 4; ++r) {
                        const int gm = m0 + i * 16 + lhi * 4 + r;
                        if (gm >= M_ROWS) continue;
                        const int bb  = gm >= NQ;
                        const int pix = gm - bb * NQ;
                        value_h[(((size_t)bb * 8 + h) * NV + pix) * 32 + ch] =
                            f2h(acc[i][j2][r] + bias);
                    }
                }
            }
        } else {
            // raw offsets / logits -> oa[M][384] f16, coalesced row-major
            #pragma unroll
            for (int j2 = 0; j2 < 2; ++j2) {
                const int gn  = n0 + wid * 32 + j2 * 16 + l15;
                const int col = gn - 256;            // 0..383
                const float bias = (col < 256) ? b_off[col] : b_attn[col - 256];
                #pragma unroll
                for (int i = 0; i < 4; ++i) {
                    #pragma unroll
                    for (int r = 0; r < 4; ++r) {
                        const int gm = m0 + i * 16 + lhi * 4 + r;
                        if (gm >= M_ROWS) continue;
                        oa[(size_t)gm * 384 + col] = f2h(acc[i][j2][r] + bias);
                    }
                }
            }
        }
    } else {
        #pragma unroll
        for (int j2 = 0; j2 < 2; ++j2) {
            const int gn = n0 + wid * 32 + j2 * 16 + l15;
            const float bias = b_out[gn];
            #pragma unroll
            for (int i = 0; i < 4; ++i) {
                #pragma unroll
                for (int r = 0; r < 4; ++r) {
                    const int gm = m0 + i * 16 + lhi * 4 + r;
                    if (gm >= M_ROWS) continue;
                    out[(size_t)gm * 256 + gn] =
                        acc[i][j2][r] + bias + qres[(size_t)gm * 256 + gn];
                }
            }
        }
    }
}

// ---------------------------------------------------------------------------
// Sampler v13 (unchanged): x-pair loads. Block = 32 rows x 1 head,
// 8 lanes/group. blockIdx.x = chunk*8 + h -> XCD pinning.
// ---------------------------------------------------------------------------
__global__ __launch_bounds__(256) void sample_kernel_v13(
    const unsigned short* __restrict__ value, // f16 [2][8][NV][32]
    const _Float16* __restrict__ oa,          // [M][384] f16
    const float* __restrict__ refp,           // [M][4][2]
    unsigned short* __restrict__ outa_h)      // [M][256] swizzled f16
{
    __shared__ uint4 sw_lds[16][34];          // [sample][group], padded

    const int bx    = blockIdx.x;
    const int h     = bx & 7;
    const int chunk = bx >> 3;
    const int g     = threadIdx.x >> 3;       // 0..31 group in block
    const int l8    = threadIdx.x & 7;        // lane in group
    const int row   = chunk * 32 + g;
    const bool valid = row < M_ROWS;

    if (valid && l8 < 4) {
        const int lvl = l8;
        const _Float16* oar = oa + (size_t)row * 384;
        const h8 oxy = *(const h8*)(oar + h * 32 + lvl * 8);
        const h4 lgh = *(const h4*)(oar + 256 + h * 16 + lvl * 4);
        const float lg0 = (float)lgh[0], lg1 = (float)lgh[1];
        const float lg2 = (float)lgh[2], lg3 = (float)lgh[3];

        float mx = fmaxf(fmaxf(lg0, lg1), fmaxf(lg2, lg3));
        mx = fmaxf(mx, __shfl_xor(mx, 1));
        mx = fmaxf(mx, __shfl_xor(mx, 2));
        const float e0 = expf(lg0 - mx);
        const float e1 = expf(lg1 - mx);
        const float e2 = expf(lg2 - mx);
        const float e3 = expf(lg3 - mx);
        float sum = e0 + e1 + e2 + e3;
        sum += __shfl_xor(sum, 1);
        sum += __shfl_xor(sum, 2);
        const float inv = 1.f / sum;

        const float2 rr = *(const float2*)(refp + (size_t)row * 8 + lvl * 2);
        const int W = lvl_W(lvl), H = lvl_H(lvl), st = lvl_start(lvl);
        const float rx = rr.x * (float)W - 0.5f;
        const float ry = rr.y * (float)H - 0.5f;

        const float sxv[4] = {(float)oxy[0] + rx, (float)oxy[2] + rx,
                              (float)oxy[4] + rx, (float)oxy[6] + rx};
        const float syv[4] = {(float)oxy[1] + ry, (float)oxy[3] + ry,
                              (float)oxy[5] + ry, (float)oxy[7] + ry};
        const float ev[4]  = {e0 * inv, e1 * inv, e2 * inv, e3 * inv};

        #pragma unroll
        for (int p = 0; p < 4; ++p) {
            const float cx = sxv[p], cy = syv[p], wz = ev[p];
            const float fx = floorf(cx), fy = floorf(cy);
            const int x0 = (int)fx, y0 = (int)fy;
            const float dx = cx - fx, dy = cy - fy;
            const float omx = 1.f - dx, omy = 1.f - dy;
            float w00 = omx * omy * wz;
            float w01 = dx  * omy * wz;
            float w10 = omx * dy  * wz;
            float w11 = dx  * dy  * wz;
            const bool vx0 = (unsigned)x0       < (unsigned)W;
            const bool vx1 = (unsigned)(x0 + 1) < (unsigned)W;
            const bool vy0 = (unsigned)y0       < (unsigned)H;
            const bool vy1 = (unsigned)(y0 + 1) < (unsigned)H;
            w00 = (vx0 & vy0) ? w00 : 0.f;
            w01 = (vx1 & vy0) ? w01 : 0.f;
            w10 = (vx0 & vy1) ? w10 : 0.f;
            w11 = (vx1 & vy1) ? w11 : 0.f;
            const int px  = min(max(x0, 0), W - 2);
            const int xs0 = min(max(x0, 0), W - 1);
            const int xs1 = min(max(x0 + 1, 0), W - 1);
            const float wlo0 = (xs0 == px ? w00 : 0.f) + (xs1 == px ? w01 : 0.f);
            const float whi0 = (xs0 == px + 1 ? w00 : 0.f) + (xs1 == px + 1 ? w01 : 0.f);
            const float wlo1 = (xs0 == px ? w10 : 0.f) + (xs1 == px ? w11 : 0.f);
            const float whi1 = (xs0 == px + 1 ? w10 : 0.f) + (xs1 == px + 1 ? w11 : 0.f);
            const int ys0 = min(max(y0, 0), H - 1);
            const int ys1 = min(max(y0 + 1, 0), H - 1);
            const unsigned pix0 = (unsigned)(st + ys0 * W + px);
            const unsigned pix1 = (unsigned)(st + ys1 * W + px);
            uint4 e;
            e.x = pix0 | (pix1 << 16);
            e.y = ((unsigned)f2h(whi0) << 16) | (unsigned)f2h(wlo0);
            e.z = ((unsigned)f2h(whi1) << 16) | (unsigned)f2h(wlo1);
            e.w = 0;
            sw_lds[lvl * 4 + p][g] = e;
        }
    }
    __syncthreads();
    if (!valid) return;

    const int b = row >= NQ;
    const char* vb = (const char*)value + (((size_t)b * 8 + h) * NV) * 64 + l8 * 16;
    const unsigned selw = 0x01000100u + (unsigned)(l8 >> 2) * 0x02020202u;

    h2 acc[4] = {};
    #pragma unroll
    for (int s = 0; s < 16; ++s) {
        const uint4 e = sw_lds[s][g];
        const uint4 u0 = *(const uint4*)(vb + ((size_t)(e.x & 0xffffu) << 6));
        const uint4 u1 = *(const uint4*)(vb + ((size_t)(e.x >> 16)     << 6));
        const unsigned w0 = __builtin_amdgcn_perm(e.y, e.y, selw);
        const unsigned w1 = __builtin_amdgcn_perm(e.z, e.z, selw);
        pkacc_u(acc, u0, w0);
        pkacc_u(acc, u1, w1);
    }

    #pragma unroll
    for (int i = 0; i < 4; ++i) {
        const unsigned a = __builtin_bit_cast(unsigned, acc[i]);
        const unsigned o = (unsigned)__shfl_xor((int)a, 4);
        acc[i] = acc[i] + __builtin_bit_cast(h2, o);
    }

    if (l8 < 4) {
        const int bytecol = h * 64 + l8 * 16;
        const int g2 = bytecol >> 7;
        const int u2 = ((bytecol >> 4) & 7) ^ (row & 7);
        uint4 d;
        d.x = __builtin_bit_cast(unsigned, acc[0]);
        d.y = __builtin_bit_cast(unsigned, acc[1]);
        d.z = __builtin_bit_cast(unsigned, acc[2]);
        d.w = __builtin_bit_cast(unsigned, acc[3]);
        *(uint4*)((char*)outa_h + (size_t)row * 512 + g2 * 128 + u2 * 16) = d;
    }
}

// ---------------------------------------------------------------------------
extern "C" void kernel_launch(void* const* d_in, const int* in_sizes, int n_in,
                              void* d_out, int out_size, void* d_ws, size_t ws_size,
                              hipStream_t stream)
{
    const float* query  = (const float*)d_in[0];
    const float* refp   = (const float*)d_in[1];
    // d_in[2] = spatial_shapes (hardcoded)
    const float* W_off  = (const float*)d_in[3];
    const float* b_off  = (const float*)d_in[4];
    const float* W_attn = (const float*)d_in[5];
    const float* b_attn = (const float*)d_in[6];
    const float* W_val  = (const float*)d_in[7];
    const float* b_val  = (const float*)d_in[8];
    const float* W_out  = (const float*)d_in[9];
    const float* b_out  = (const float*)d_in[10];
    float* out = (float*)d_out;

    char* p = (char*)d_ws;
    unsigned short* oabf    = (unsigned short*)p;  p += (size_t)M_ROWS * 512; // sampler out
    unsigned short* value_h = (unsigned short*)p;  p += (size_t)M_ROWS * 512;
    unsigned short* Wcat    = (unsigned short*)p;  p += (size_t)640 * 512;
    unsigned short* WoutT   = (unsigned short*)p;  p += (size_t)256 * 512;
    unsigned short* oa      = (unsigned short*)p;  p += (size_t)M_ROWS * 384 * 2;

    const dim3 blk(256);

    // 0) weights-only packing (tiny)
    pack_weights_kernel<<<(896 * 32 + 255) / 256, blk, 0, stream>>>(
        W_val, W_off, W_attn, W_out, Wcat, WoutT);

    // 1) fused projections; 64x128 tiles; A reg-staged from query f32
    mfma_gemm_kernel<0><<<dim3(MT * 5), blk, 0, stream>>>(
        query, nullptr, Wcat, value_h, oa, b_val, b_off, b_attn,
        nullptr, nullptr, nullptr);

    // 2) sampler: 32 rows x 1 head per block; blockIdx = chunk*8 + h (XCD pin)
    const int chunks = (M_ROWS + 31) / 32;
    sample_kernel_v13<<<chunks * 8, blk, 0, stream>>>(
        value_h, (const _Float16*)oa, refp, oabf);

    // 3) out projection + bias + f32 residual; 64x128 tiles
    mfma_gemm_kernel<1><<<dim3(MT * 2), blk, 0, stream>>>(
        nullptr, oabf, WoutT, nullptr, nullptr, nullptr, nullptr, nullptr,
        b_out, query, out);
}

// Round 19
// 137.539 us; speedup vs baseline: 1.3894x; 1.3894x over previous
//
#include <hip/hip_runtime.h>
#include <math.h>

#define HEADS     8
#define LEVELS    4
#define POINTS    4
#define HEAD_DIM  32
#define EMBED     256
#define NQ        19947
#define NV        19947
#define BS        2
#define M_ROWS    (BS * NQ)   // 39894
#define MT        624         // M tiles of 64 rows (624*64 = 39936)

typedef _Float16 h8 __attribute__((ext_vector_type(8)));
typedef _Float16 h4 __attribute__((ext_vector_type(4)));
typedef _Float16 h2 __attribute__((ext_vector_type(2)));
typedef float    f32x4 __attribute__((ext_vector_type(4)));
typedef unsigned short ushort8 __attribute__((ext_vector_type(8)));

static __device__ __forceinline__ int lvl_H(int l) {
    constexpr int v[4] = {100, 50, 25, 13}; return v[l];
}
static __device__ __forceinline__ int lvl_W(int l) {
    constexpr int v[4] = {150, 75, 38, 19}; return v[l];
}
static __device__ __forceinline__ int lvl_start(int l) {
    constexpr int v[4] = {0, 15000, 18750, 19700}; return v[l];
}

// f32 -> f16 bits (RTNE via hardware cvt)
static __device__ __forceinline__ unsigned short f2h(float f) {
    _Float16 h = (_Float16)f;
    return __builtin_bit_cast(unsigned short, h);
}

// async global->LDS, 16B per lane
static __device__ __forceinline__ void gload_lds16(const void* g, void* l) {
    __builtin_amdgcn_global_load_lds(
        (const __attribute__((address_space(1))) void*)g,
        (__attribute__((address_space(3))) void*)l, 16, 0, 0);
}

// packed f16 FMA, weight pre-splatted as u32 {w,w}
static __device__ __forceinline__ void pkacc_u(h2* acc, uint4 u, unsigned wbits) {
    const h2 wv = __builtin_bit_cast(h2, wbits);
    acc[0] = __builtin_bit_cast(h2, u.x) * wv + acc[0];
    acc[1] = __builtin_bit_cast(h2, u.y) * wv + acc[1];
    acc[2] = __builtin_bit_cast(h2, u.z) * wv + acc[2];
    acc[3] = __builtin_bit_cast(h2, u.w) * wv + acc[3];
}

// ---------------------------------------------------------------------------
// Pack weights only: Wcat[640][256] = [W_val^T; W_off^T; W_attn^T], WoutT.
// ---------------------------------------------------------------------------
__global__ __launch_bounds__(256) void pack_weights_kernel(
    const float* __restrict__ Wv, const float* __restrict__ Wo,
    const float* __restrict__ Wa, const float* __restrict__ Wout,
    unsigned short* __restrict__ Wcat, unsigned short* __restrict__ WoutT)
{
    const int tid = blockIdx.x * 256 + threadIdx.x;
    if (tid >= 896 * 32) return;
    const int row = tid >> 5;
    const int k8  = tid & 31;
    const float* src; int n_local, N; unsigned short* dstb; int r_local;
    if (row < 256)      { src = Wv;   n_local = row;       N = 256; dstb = Wcat;  r_local = row; }
    else if (row < 512) { src = Wo;   n_local = row - 256; N = 256; dstb = Wcat;  r_local = row; }
    else if (row < 640) { src = Wa;   n_local = row - 512; N = 128; dstb = Wcat;  r_local = row; }
    else                { src = Wout; n_local = row - 640; N = 256; dstb = WoutT; r_local = row - 640; }
    const int k = k8 * 8;
    ushort8 o;
    #pragma unroll
    for (int j = 0; j < 8; ++j)
        o[j] = f2h(src[(size_t)(k + j) * N + n_local]);
    const int g  = k8 >> 3;
    const int u2 = (k8 & 7) ^ (r_local & 7);
    *(ushort8*)((char*)dstb + (size_t)r_local * 512 + g * 128 + u2 * 16) = o;
}

// ---------------------------------------------------------------------------
// f16 MFMA GEMM, 64x128 tile (BM=64), BK=64, 4 waves (each 64x32), LDS 24KB
// -> ~5 blocks/CU resident so per-block barrier-drain stalls overlap.
// 1D grid, XCD-affinity remap (all by of one bx on the same XCD).
// EPI 0 (NB=5): A reg-staged from query f32 (cvt f16 + swizzled ds_write).
//               by<2: value -> f16 [2][8][NV][32]
//               by>=2: raw projections + bias -> oa[M][384] f16
// EPI 1 (NB=2): A via gload_lds from swizzled f16 (sampler out);
//               out = acc + b_out + query (f32 residual)
// ---------------------------------------------------------------------------
template <int EPI>
__global__ __launch_bounds__(256) void mfma_gemm_kernel(
    const float* __restrict__ Aq,            // EPI0: query f32 [M][256]
    const unsigned short* __restrict__ Ah,   // EPI1: oabf (swizzled f16)
    const unsigned short* __restrict__ Bh,
    unsigned short* __restrict__ value_h,    // EPI0
    unsigned short* __restrict__ oa,         // EPI0: [M][384] f16
    const float* __restrict__ b_val, const float* __restrict__ b_off,
    const float* __restrict__ b_attn,
    const float* __restrict__ b_out,
    const float* __restrict__ qres,          // EPI1: query f32 residual
    float* __restrict__ out)
{
    __shared__ alignas(16) char As[8192];    // 64 rows x 64 k f16
    __shared__ alignas(16) char Bs[16384];   // 128 rows x 64 k f16

    constexpr int NB = (EPI == 0) ? 5 : 2;
    const int id  = blockIdx.x;
    const int grp = id / (8 * NB);
    const int rem = id - grp * (8 * NB);
    const int bx  = grp * 8 + (rem & 7);
    const int by  = rem >> 3;

    const int t    = threadIdx.x;
    const int wid  = t >> 6;
    const int lane = t & 63;
    const int l15  = lane & 15;
    const int lhi  = lane >> 4;
    const int m0   = bx * 64;
    const int n0   = by * 128;

    f32x4 acc[4][2] = {};

    auto stage = [&](int ks) {
        // A: 64 rows x 8 units(16B) = 512 units, 2 per thread
        #pragma unroll
        for (int j = 0; j < 2; ++j) {
            const int q  = j * 256 + t;
            const int tr = q >> 3;
            const int u  = q & 7;
            int gr = m0 + tr; gr = gr < M_ROWS ? gr : (M_ROWS - 1);
            if (EPI == 0) {
                const float* src = Aq + (size_t)gr * 256 + ks * 64 + u * 8;
                const float4 v0 = *(const float4*)(src);
                const float4 v1 = *(const float4*)(src + 4);
                ushort8 o;
                o[0] = f2h(v0.x); o[1] = f2h(v0.y);
                o[2] = f2h(v0.z); o[3] = f2h(v0.w);
                o[4] = f2h(v1.x); o[5] = f2h(v1.y);
                o[6] = f2h(v1.z); o[7] = f2h(v1.w);
                *(ushort8*)&As[tr * 128 + (unsigned)(u ^ (tr & 7)) * 16] = o;
            } else {
                gload_lds16((const char*)Ah + (size_t)gr * 512 + ks * 128 + u * 16,
                            As + (j * 256 + wid * 64) * 16);
            }
        }
        // B: 128 rows x 8 units = 1024 units, 4 per thread
        #pragma unroll
        for (int j = 0; j < 4; ++j) {
            const int q  = j * 256 + t;
            const int tr = q >> 3;
            const int u  = q & 7;
            const int gn = n0 + tr;
            gload_lds16((const char*)Bh + (size_t)gn * 512 + ks * 128 + u * 16,
                        Bs + (j * 256 + wid * 64) * 16);
        }
    };

    stage(0);
    for (int ks = 0; ks < 4; ++ks) {
        __syncthreads();
        #pragma unroll
        for (int kc = 0; kc < 2; ++kc) {
            h8 a[4], b[2];
            #pragma unroll
            for (int i = 0; i < 4; ++i) {
                const int tr = i * 16 + l15;
                const int ua = (kc * 4 + lhi) ^ (tr & 7);
                a[i] = *(const h8*)&As[tr * 128 + ua * 16];
            }
            #pragma unroll
            for (int j2 = 0; j2 < 2; ++j2) {
                const int tn = wid * 32 + j2 * 16 + l15;
                const int ub = (kc * 4 + lhi) ^ (tn & 7);
                b[j2] = *(const h8*)&Bs[tn * 128 + ub * 16];
            }
            #pragma unroll
            for (int i = 0; i < 4; ++i)
                #pragma unroll
                for (int j2 = 0; j2 < 2; ++j2)
                    acc[i][j2] = __builtin_amdgcn_mfma_f32_16x16x32_f16(
                        a[i], b[j2], acc[i][j2], 0, 0, 0);
        }
        if (ks < 3) { __syncthreads(); stage(ks + 1); }
    }

    if (EPI == 0) {
        if (by < 2) {
            // value projection -> f16 [2][8][NV][32]
            #pragma unroll
            for (int j2 = 0; j2 < 2; ++j2) {
                const int gn = n0 + wid * 32 + j2 * 16 + l15;
                const float bias = b_val[gn];
                const int h = gn >> 5, ch = gn & 31;
                #pragma unroll
                for (int i = 0; i < 4; ++i) {
                    #pragma unroll
                    for (int r = 0; r < 4; ++r) {
                        const int gm = m0 + i * 16 + lhi * 4 + r;
                        if (gm >= M_ROWS) continue;
                        const int bb  = gm >= NQ;
                        const int pix = gm - bb * NQ;
                        value_h[(((size_t)bb * 8 + h) * NV + pix) * 32 + ch] =
                            f2h(acc[i][j2][r] + bias);
                    }
                }
            }
        } else {
            // raw offsets / logits -> oa[M][384] f16, coalesced row-major
            #pragma unroll
            for (int j2 = 0; j2 < 2; ++j2) {
                const int gn  = n0 + wid * 32 + j2 * 16 + l15;
                const int col = gn - 256;            // 0..383
                const float bias = (col < 256) ? b_off[col] : b_attn[col - 256];
                #pragma unroll
                for (int i = 0; i < 4; ++i) {
                    #pragma unroll
                    for (int r = 0; r < 4; ++r) {
                        const int gm = m0 + i * 16 + lhi * 4 + r;
                        if (gm >= M_ROWS) continue;
                        oa[(size_t)gm * 384 + col] = f2h(acc[i][j2][r] + bias);
                    }
                }
            }
        }
    } else {
        #pragma unroll
        for (int j2 = 0; j2 < 2; ++j2) {
            const int gn = n0 + wid * 32 + j2 * 16 + l15;
            const float bias = b_out[gn];
            #pragma unroll
            for (int i = 0; i < 4; ++i) {
                #pragma unroll
                for (int r = 0; r < 4; ++r) {
                    const int gm = m0 + i * 16 + lhi * 4 + r;
                    if (gm >= M_ROWS) continue;
                    out[(size_t)gm * 256 + gn] =
                        acc[i][j2][r] + bias + qres[(size_t)gm * 256 + gn];
                }
            }
        }
    }
}

// ---------------------------------------------------------------------------
// Sampler v13 (unchanged): x-pair loads. Block = 32 rows x 1 head,
// 8 lanes/group. blockIdx.x = chunk*8 + h -> XCD pinning.
// ---------------------------------------------------------------------------
__global__ __launch_bounds__(256) void sample_kernel_v13(
    const unsigned short* __restrict__ value, // f16 [2][8][NV][32]
    const _Float16* __restrict__ oa,          // [M][384] f16
    const float* __restrict__ refp,           // [M][4][2]
    unsigned short* __restrict__ outa_h)      // [M][256] swizzled f16
{
    __shared__ uint4 sw_lds[16][34];          // [sample][group], padded

    const int bx    = blockIdx.x;
    const int h     = bx & 7;
    const int chunk = bx >> 3;
    const int g     = threadIdx.x >> 3;       // 0..31 group in block
    const int l8    = threadIdx.x & 7;        // lane in group
    const int row   = chunk * 32 + g;
    const bool valid = row < M_ROWS;

    if (valid && l8 < 4) {
        const int lvl = l8;
        const _Float16* oar = oa + (size_t)row * 384;
        const h8 oxy = *(const h8*)(oar + h * 32 + lvl * 8);
        const h4 lgh = *(const h4*)(oar + 256 + h * 16 + lvl * 4);
        const float lg0 = (float)lgh[0], lg1 = (float)lgh[1];
        const float lg2 = (float)lgh[2], lg3 = (float)lgh[3];

        float mx = fmaxf(fmaxf(lg0, lg1), fmaxf(lg2, lg3));
        mx = fmaxf(mx, __shfl_xor(mx, 1));
        mx = fmaxf(mx, __shfl_xor(mx, 2));
        const float e0 = expf(lg0 - mx);
        const float e1 = expf(lg1 - mx);
        const float e2 = expf(lg2 - mx);
        const float e3 = expf(lg3 - mx);
        float sum = e0 + e1 + e2 + e3;
        sum += __shfl_xor(sum, 1);
        sum += __shfl_xor(sum, 2);
        const float inv = 1.f / sum;

        const float2 rr = *(const float2*)(refp + (size_t)row * 8 + lvl * 2);
        const int W = lvl_W(lvl), H = lvl_H(lvl), st = lvl_start(lvl);
        const float rx = rr.x * (float)W - 0.5f;
        const float ry = rr.y * (float)H - 0.5f;

        const float sxv[4] = {(float)oxy[0] + rx, (float)oxy[2] + rx,
                              (float)oxy[4] + rx, (float)oxy[6] + rx};
        const float syv[4] = {(float)oxy[1] + ry, (float)oxy[3] + ry,
                              (float)oxy[5] + ry, (float)oxy[7] + ry};
        const float ev[4]  = {e0 * inv, e1 * inv, e2 * inv, e3 * inv};

        #pragma unroll
        for (int p = 0; p < 4; ++p) {
            const float cx = sxv[p], cy = syv[p], wz = ev[p];
            const float fx = floorf(cx), fy = floorf(cy);
            const int x0 = (int)fx, y0 = (int)fy;
            const float dx = cx - fx, dy = cy - fy;
            const float omx = 1.f - dx, omy = 1.f - dy;
            float w00 = omx * omy * wz;
            float w01 = dx  * omy * wz;
            float w10 = omx * dy  * wz;
            float w11 = dx  * dy  * wz;
            const bool vx0 = (unsigned)x0       < (unsigned)W;
            const bool vx1 = (unsigned)(x0 + 1) < (unsigned)W;
            const bool vy0 = (unsigned)y0       < (unsigned)H;
            const bool vy1 = (unsigned)(y0 + 1) < (unsigned)H;
            w00 = (vx0 & vy0) ? w00 : 0.f;
            w01 = (vx1 & vy0) ? w01 : 0.f;
            w10 = (vx0 & vy1) ? w10 : 0.f;
            w11 = (vx1 & vy1) ? w11 : 0.f;
            const int px  = min(max(x0, 0), W - 2);
            const int xs0 = min(max(x0, 0), W - 1);
            const int xs1 = min(max(x0 + 1, 0), W - 1);
            const float wlo0 = (xs0 == px ? w00 : 0.f) + (xs1 == px ? w01 : 0.f);
            const float whi0 = (xs0 == px + 1 ? w00 : 0.f) + (xs1 == px + 1 ? w01 : 0.f);
            const float wlo1 = (xs0 == px ? w10 : 0.f) + (xs1 == px ? w11 : 0.f);
            const float whi1 = (xs0 == px + 1 ? w10 : 0.f) + (xs1 == px + 1 ? w11 : 0.f);
            const int ys0 = min(max(y0, 0), H - 1);
            const int ys1 = min(max(y0 + 1, 0), H - 1);
            const unsigned pix0 = (unsigned)(st + ys0 * W + px);
            const unsigned pix1 = (unsigned)(st + ys1 * W + px);
            uint4 e;
            e.x = pix0 | (pix1 << 16);
            e.y = ((unsigned)f2h(whi0) << 16) | (unsigned)f2h(wlo0);
            e.z = ((unsigned)f2h(whi1) << 16) | (unsigned)f2h(wlo1);
            e.w = 0;
            sw_lds[lvl * 4 + p][g] = e;
        }
    }
    __syncthreads();
    if (!valid) return;

    const int b = row >= NQ;
    const char* vb = (const char*)value + (((size_t)b * 8 + h) * NV) * 64 + l8 * 16;
    const unsigned selw = 0x01000100u + (unsigned)(l8 >> 2) * 0x02020202u;

    h2 acc[4] = {};
    #pragma unroll
    for (int s = 0; s < 16; ++s) {
        const uint4 e = sw_lds[s][g];
        const uint4 u0 = *(const uint4*)(vb + ((size_t)(e.x & 0xffffu) << 6));
        const uint4 u1 = *(const uint4*)(vb + ((size_t)(e.x >> 16)     << 6));
        const unsigned w0 = __builtin_amdgcn_perm(e.y, e.y, selw);
        const unsigned w1 = __builtin_amdgcn_perm(e.z, e.z, selw);
        pkacc_u(acc, u0, w0);
        pkacc_u(acc, u1, w1);
    }

    #pragma unroll
    for (int i = 0; i < 4; ++i) {
        const unsigned a = __builtin_bit_cast(unsigned, acc[i]);
        const unsigned o = (unsigned)__shfl_xor((int)a, 4);
        acc[i] = acc[i] + __builtin_bit_cast(h2, o);
    }

    if (l8 < 4) {
        const int bytecol = h * 64 + l8 * 16;
        const int g2 = bytecol >> 7;
        const int u2 = ((bytecol >> 4) & 7) ^ (row & 7);
        uint4 d;
        d.x = __builtin_bit_cast(unsigned, acc[0]);
        d.y = __builtin_bit_cast(unsigned, acc[1]);
        d.z = __builtin_bit_cast(unsigned, acc[2]);
        d.w = __builtin_bit_cast(unsigned, acc[3]);
        *(uint4*)((char*)outa_h + (size_t)row * 512 + g2 * 128 + u2 * 16) = d;
    }
}

// ---------------------------------------------------------------------------
extern "C" void kernel_launch(void* const* d_in, const int* in_sizes, int n_in,
                              void* d_out, int out_size, void* d_ws, size_t ws_size,
                              hipStream_t stream)
{
    const float* query  = (const float*)d_in[0];
    const float* refp   = (const float*)d_in[1];
    // d_in[2] = spatial_shapes (hardcoded)
    const float* W_off  = (const float*)d_in[3];
    const float* b_off  = (const float*)d_in[4];
    const float* W_attn = (const float*)d_in[5];
    const float* b_attn = (const float*)d_in[6];
    const float* W_val  = (const float*)d_in[7];
    const float* b_val  = (const float*)d_in[8];
    const float* W_out  = (const float*)d_in[9];
    const float* b_out  = (const float*)d_in[10];
    float* out = (float*)d_out;

    char* p = (char*)d_ws;
    unsigned short* oabf    = (unsigned short*)p;  p += (size_t)M_ROWS * 512; // sampler out
    unsigned short* value_h = (unsigned short*)p;  p += (size_t)M_ROWS * 512;
    unsigned short* Wcat    = (unsigned short*)p;  p += (size_t)640 * 512;
    unsigned short* WoutT   = (unsigned short*)p;  p += (size_t)256 * 512;
    unsigned short* oa      = (unsigned short*)p;  p += (size_t)M_ROWS * 384 * 2;

    const dim3 blk(256);

    // 0) weights-only packing (tiny)
    pack_weights_kernel<<<(896 * 32 + 255) / 256, blk, 0, stream>>>(
        W_val, W_off, W_attn, W_out, Wcat, WoutT);

    // 1) fused projections; 64x128 tiles; A reg-staged from query f32
    mfma_gemm_kernel<0><<<dim3(MT * 5), blk, 0, stream>>>(
        query, nullptr, Wcat, value_h, oa, b_val, b_off, b_attn,
        nullptr, nullptr, nullptr);

    // 2) sampler: 32 rows x 1 head per block; blockIdx = chunk*8 + h (XCD pin)
    const int chunks = (M_ROWS + 31) / 32;
    sample_kernel_v13<<<chunks * 8, blk, 0, stream>>>(
        value_h, (const _Float16*)oa, refp, oabf);

    // 3) out projection + bias + f32 residual; 64x128 tiles
    mfma_gemm_kernel<1><<<dim3(MT * 2), blk, 0, stream>>>(
        nullptr, oabf, WoutT, nullptr, nullptr, nullptr, nullptr, nullptr,
        b_out, query, out);
}